// Round 1
// baseline (171.695 us; speedup 1.0000x reference)
//
#include <hip/hip_runtime.h>

// Problem constants (from reference)
#define NB 64      // B
#define NC 23      // C
#define NL 26000   // L
#define ND 64      // D
#define NE 512     // E
#define NK 3       // K

// ---------------------------------------------------------------------------
// Kernel 1: e[b,c,k] = fc_b[k] + sum_d We[k,d] * (eos_b[d] + sum_e eos_emb[b,c,e]*eos_W[d,e])
// One 64-thread block per (b,c) pair; lane d computes eos[d], then 3 wave
// reductions produce e[b,c,0..2].  ~48M MACs total, L2-resident.
// ---------------------------------------------------------------------------
__global__ __launch_bounds__(64) void eos_e_kernel(
    const float* __restrict__ eos_emb,  // [B][C][E]
    const float* __restrict__ eos_W,    // [D][E]
    const float* __restrict__ eos_b,    // [D]
    const float* __restrict__ fc_W,     // [K][2D]
    const float* __restrict__ fc_b,     // [K]
    float* __restrict__ e_out)          // [B*C][K]
{
    const int bc = blockIdx.x;          // b*C + c
    const int d  = threadIdx.x;         // 0..63

    __shared__ float xs[NE];
    float4* xs4 = reinterpret_cast<float4*>(xs);
    const float4* src = reinterpret_cast<const float4*>(eos_emb + (size_t)bc * NE);
    for (int i = d; i < NE / 4; i += 64) xs4[i] = src[i];
    __syncthreads();

    const float4* wrow = reinterpret_cast<const float4*>(eos_W + (size_t)d * NE);
    float acc = 0.f;
    #pragma unroll 8
    for (int i = 0; i < NE / 4; ++i) {
        float4 w = wrow[i];
        float4 x = xs4[i];
        acc += w.x * x.x;
        acc += w.y * x.y;
        acc += w.z * x.z;
        acc += w.w * x.w;
    }
    const float eosd = acc + eos_b[d];

    #pragma unroll
    for (int k = 0; k < NK; ++k) {
        float p = eosd * fc_W[k * (2 * ND) + ND + d];   // We[k][d]
        #pragma unroll
        for (int off = 32; off > 0; off >>= 1) p += __shfl_xor(p, off, 64);
        if (d == 0) e_out[(size_t)bc * NK + k] = p + fc_b[k];
    }
}

// ---------------------------------------------------------------------------
// Kernel 2: for each (c,l): a_k = dot(emb_table[bin_ids[c,l]], Wb[k]); then
// out[b,c,l,k] = relu(a_k + e[b,c,k]) for all b.  emb_table read exactly once,
// output written exactly once -> write-BW bound (~460 MB stores).
// ---------------------------------------------------------------------------
__global__ __launch_bounds__(256) void decoder_main_kernel(
    const int*   __restrict__ bin_ids,    // [C][L]
    const float* __restrict__ emb_table,  // [V][D]
    const float* __restrict__ fc_W,       // [K][2D]
    const float* __restrict__ e_in,       // [B][C][K]
    float* __restrict__ out)              // [B][C][L][K]
{
    const int c   = blockIdx.y;
    const int tid = threadIdx.x;
    const int l   = blockIdx.x * 256 + tid;

    __shared__ float wb[NK][ND];     // Wb, broadcast-read
    __shared__ float es[NB * NK];    // e[:, c, :]

    if (tid < NK * ND)
        wb[tid / ND][tid % ND] = fc_W[(tid / ND) * (2 * ND) + (tid % ND)];
    if (tid < NB * NK) {
        int b = tid / NK, k = tid % NK;
        es[tid] = e_in[((size_t)b * NC + c) * NK + k];
    }
    __syncthreads();
    if (l >= NL) return;

    const int row = bin_ids[(size_t)c * NL + l];
    const float4* er = reinterpret_cast<const float4*>(emb_table + (size_t)row * ND);
    const float4* w0 = reinterpret_cast<const float4*>(wb[0]);
    const float4* w1 = reinterpret_cast<const float4*>(wb[1]);
    const float4* w2 = reinterpret_cast<const float4*>(wb[2]);

    float a0 = 0.f, a1 = 0.f, a2 = 0.f;
    #pragma unroll
    for (int i = 0; i < ND / 4; ++i) {
        float4 v  = er[i];
        float4 p0 = w0[i], p1 = w1[i], p2 = w2[i];
        a0 += v.x * p0.x + v.y * p0.y + v.z * p0.z + v.w * p0.w;
        a1 += v.x * p1.x + v.y * p1.y + v.z * p1.z + v.w * p1.w;
        a2 += v.x * p2.x + v.y * p2.y + v.z * p2.z + v.w * p2.w;
    }

    size_t obase = ((size_t)c * NL + l) * NK;           // b = 0 slot
    const size_t bstride = (size_t)NC * NL * NK;        // advance one b
    #pragma unroll 4
    for (int b = 0; b < NB; ++b) {
        const float e0 = es[b * NK + 0];
        const float e1 = es[b * NK + 1];
        const float e2 = es[b * NK + 2];
        out[obase + 0] = fmaxf(a0 + e0, 0.f);
        out[obase + 1] = fmaxf(a1 + e1, 0.f);
        out[obase + 2] = fmaxf(a2 + e2, 0.f);
        obase += bstride;
    }
}

extern "C" void kernel_launch(void* const* d_in, const int* in_sizes, int n_in,
                              void* d_out, int out_size, void* d_ws, size_t ws_size,
                              hipStream_t stream) {
    const float* eos_emb   = (const float*)d_in[0];
    const int*   bin_ids   = (const int*)  d_in[1];
    const float* emb_table = (const float*)d_in[2];
    const float* eos_W     = (const float*)d_in[3];
    const float* eos_b     = (const float*)d_in[4];
    const float* fc_W      = (const float*)d_in[5];
    const float* fc_b      = (const float*)d_in[6];
    float*       out       = (float*)d_out;
    float*       e_ws      = (float*)d_ws;   // B*C*K floats = 17.7 KB

    eos_e_kernel<<<NB * NC, 64, 0, stream>>>(eos_emb, eos_W, eos_b, fc_W, fc_b, e_ws);

    dim3 grid((NL + 255) / 256, NC);
    decoder_main_kernel<<<grid, 256, 0, stream>>>(bin_ids, emb_table, fc_W, e_ws, out);
}